// Round 9
// baseline (214.102 us; speedup 1.0000x reference)
//
#include <hip/hip_runtime.h>
#include <math.h>

#define B 2
#define L 1024
#define X 4
#define E 128
#define Y 4
#define SCALE 0.08838834764831845f  // 1/sqrt(128)

typedef unsigned short u16;
typedef __attribute__((ext_vector_type(8))) short bf16frag;   // 8 bf16 (4 VGPRs)
typedef __attribute__((ext_vector_type(4))) float floatx4;    // 4 fp32 acc

// round-to-nearest-even f32 -> bf16
static __device__ __forceinline__ u16 bfr(float f) {
  union { float f; unsigned u; } c; c.f = f;
  unsigned r = (c.u + 0x7fffu + ((c.u >> 16) & 1u)) >> 16;
  return (u16)r;
}

// ---------------- K_PREP: fused {series fill, Wv transpose, q/k bf16 convert, ------
// V transpose, Gaussian prior, Wk fragment-pack}. Branch is block-uniform.
// Ranges: [0,8192) fill | [8192,8208) wvt | [8208,9232) qk conv | [9232,9360) vtrans
//         | [9360,17552) prior | [17552,17560) wk-frag.
__global__ __launch_bounds__(256) void k_prep(const float* __restrict__ q,
                                              const float* __restrict__ key,
                                              const float* __restrict__ value,
                                              const float* __restrict__ sigma,
                                              const float* __restrict__ Wv,
                                              const float* __restrict__ Wk,
                                              float4* __restrict__ sout4,
                                              u16* __restrict__ qkb,
                                              float* __restrict__ colsum,
                                              u16* __restrict__ vt,
                                              float4* __restrict__ wv4t,
                                              u16* __restrict__ wkf,
                                              float* __restrict__ prior,
                                              float* __restrict__ sigout) {
  __shared__ float shp[2];   // prior branch only: {coef, inv2s2}
  const int bid = blockIdx.x;
  const int t = threadIdx.x;
  if (bid < 8192) {
    // series_out is identically 0.25 (mean over the softmax axis)
    sout4[bid * 256 + t] = make_float4(0.25f, 0.25f, 0.25f, 0.25f);
  } else if (bid < 8208) {
    // wv4t[e4*128+f] = float4{Wv[f][4e4..4e4+3]} (kills k6's 64-line gather)
    const int idx = (bid - 8192) * 256 + t;
    const int e4 = idx >> 7, f = idx & 127;
    wv4t[idx] = *(const float4*)(Wv + f * E + e4 * 4);
  } else if (bid < 9232) {
    // q,key fp32 [b,l,x,e] -> bf16 [bx][l][e]; zero colsum
    if (bid == 8208) colsum[t] = 0.f;
    const int f = (bid - 8208) * 256 + t;   // 262144 total
    const int row = f >> 4, c8 = (f & 15) * 8;
    const int sel = row >> 13, row2 = row & 8191;   // row2 = b*4096 + l*4 + x
    const int b = row2 >> 12, l = (row2 >> 2) & 1023, x = row2 & 3;
    const float* src = (sel ? key : q) + (size_t)row2 * E + c8;
    float4 v0 = *(const float4*)src;
    float4 v1 = *(const float4*)(src + 4);
    u16 us[8] = {bfr(v0.x), bfr(v0.y), bfr(v0.z), bfr(v0.w),
                 bfr(v1.x), bfr(v1.y), bfr(v1.z), bfr(v1.w)};
    u16* dst = qkb + (size_t)(sel * 8192 + (b * 4 + x) * 1024 + l) * E + c8;
    *(uint4*)dst = *(uint4*)us;
  } else if (bid < 9360) {
    // vt[(b*4+y)*128+e][s] = bf16(value[b,s,y,e]); 128 blocks x 256 thr
    const int blk = bid - 9232;
    const int by = blk >> 4, sc2 = blk & 15;
    const int b = by >> 2, y = by & 3;
    const int e = t & 127, sh = t >> 7;
    const int s0 = sc2 * 64 + sh * 32;
    u16 us[32];
#pragma unroll 8
    for (int ss = 0; ss < 32; ++ss)
      us[ss] = bfr(value[((size_t)((b * L + s0 + ss) * Y + y)) * E + e]);
    u16* dst = vt + ((size_t)(by * E + e)) * L + s0;
#pragma unroll
    for (int i = 0; i < 4; ++i) *(uint4*)(dst + i * 8) = *(uint4*)&us[i * 8];
  } else if (bid < 17552) {
    // Gaussian prior + sig output. f64 sigma chain computed ONCE per block,
    // broadcast via LDS.
    const int row = bid - 9360;
    const int bx = row >> 10;
    const int i = row & 1023;
    const int b = bx >> 2, x = bx & 3;
    if (t == 0) {
      const double sv = (double)sigma[((size_t)(b * L + i)) * X + x];
      const double sg = 1.0 / (1.0 + exp(-5.0 * sv)) + 1e-5;
      const double s3 = exp(sg * 1.0986122886681098) - 1.0;
      shp[0] = (float)(1.0 / (2.5066282746310002 * s3));
      shp[1] = (float)(0.5 / (s3 * s3));
      sigout[row] = (float)s3;
    }
    __syncthreads();
    const float coef = shp[0], inv2s2 = shp[1];
    const float di = (float)i;
    const int j0 = t * 4;
    float4 o; float d;
    d = di - (float)(j0 + 0); o.x = coef * __expf(-d * d * inv2s2);
    d = di - (float)(j0 + 1); o.y = coef * __expf(-d * d * inv2s2);
    d = di - (float)(j0 + 2); o.z = coef * __expf(-d * d * inv2s2);
    d = di - (float)(j0 + 3); o.w = coef * __expf(-d * d * inv2s2);
    *(float4*)(prior + (size_t)row * 1024 + j0) = o;
  } else {
    // wkf: Wk packed in MFMA-B-fragment order so k134's B1 loads are coalesced.
    const int idx = (bid - 17552) * 256 + t;   // [0,2048)
    const int slot = idx >> 6, lane2 = idx & 63;
    const int col = lane2 & 15, quad = lane2 >> 4;
    const int eg = slot >> 4, ft = (slot >> 2) & 3, k = slot & 3;
    const float* src = Wk + (size_t)((eg * 4 + ft) * 16 + col) * E + k * 32 + quad * 8;
    float4 w0 = *(const float4*)src;
    float4 w1 = *(const float4*)(src + 4);
    u16 us[8] = {bfr(w0.x), bfr(w0.y), bfr(w0.z), bfr(w0.w),
                 bfr(w1.x), bfr(w1.y), bfr(w1.z), bfr(w1.w)};
    *(uint4*)(wkf + (size_t)idx * 8) = *(uint4*)us;
  }
}

// ---------------- K134: FUSED stage-1 (QK^T + exp + rowsum + PV) + Wk proj ----------
// Replaces k1+k34: eliminates the 8 MB sbh intermediate (write + NY re-reads) and a
// launch gap. Per block (b, p=(x,y), lt): loop 64-wide s-chunks {stage K,V | bar |
// P = exp(mfma(q,K)*SCALE) -> pT, rowsum in regs | bar | PV mfma accumulate}, then
// reduce rowsum (k1's shfl+LDS pattern), normalize into Rt, and k34's phase B
// (kp via wkf MFMAs, rt transpose, p==0 colsum) unchanged. P is recomputed per
// (x,y) pair (20 vs 8 tiles, +~3 GF) -- cheaper than the sbh round-trip + k1.
// All 640 blocks now do IDENTICAL work (no x-dependent imbalance).
__global__ __launch_bounds__(256) void k134_fused(const u16* __restrict__ qb,
                                                  const u16* __restrict__ kb,
                                                  const u16* __restrict__ vt,
                                                  const u16* __restrict__ wkf,
                                                  const float* __restrict__ bk,
                                                  u16* __restrict__ kp_bf,
                                                  u16* __restrict__ rt_bf,
                                                  float* __restrict__ colsum) {
  // LDS: Kt[64][136]u16 @0 (17408) | Vt[128][72]u16 @17408 (18432) |
  //      pT[32][72]u16 @35840 (4608) | red[4][16]f32 @40448 | inv[32]f32 @40704
  // Rt[32][132]f32 (16896) overlays Kt after the reduce barriers. Total 40832 B.
  __shared__ __align__(16) unsigned char smem[40832];
  u16 (*Kt)[136] = (u16(*)[136])smem;
  u16 (*Vt)[72]  = (u16(*)[72])(smem + 17408);
  u16 (*pT)[72]  = (u16(*)[72])(smem + 35840);
  float* red     = (float*)(smem + 40448);   // [4][16]
  float* inv_l   = (float*)(smem + 40704);   // [32]
  float (*Rt)[132] = (float(*)[132])smem;    // overlay
  const int t = threadIdx.x;
  const int blk = (blockIdx.x & 7) * 80 + (blockIdx.x >> 3);  // bijective, 640=8*80
  const int lt = blk & 31;
  const int cp = blk >> 5;                     // [0,20) = b*10 + p
  const int b = cp / 10, p = cp % 10;
  const int x = (p >= 6) ? 3 : (p >= 3) ? 2 : (p >= 1) ? 1 : 0;
  const int y = p - ((x * (x + 1)) >> 1);
  const int bx = b * 4 + x;                    // qb/kb batch
  const int by = b * 4 + y;                    // vt batch
  const int l0 = lt * 32;
  const int lane = t & 63, w = t >> 6;
  const int col = lane & 15, quad = lane >> 4;
  const int lw = w >> 1, mt = w & 1, eg = w & 1;

  // A-frags: q rows l0+lw*16+col (bf16, pre-converted) -- k5's af pattern from qb
  bf16frag af[4];
#pragma unroll
  for (int k = 0; k < 4; ++k)
    af[k] = *(const bf16frag*)(qb + (size_t)(bx * L + l0 + lw * 16 + col) * E + k * 32 + quad * 8);

  floatx4 vf[4];
#pragma unroll
  for (int i = 0; i < 4; ++i) vf[i] = (floatx4){0.f, 0.f, 0.f, 0.f};
  float rs[4] = {0.f, 0.f, 0.f, 0.f};

  for (int sc = 0; sc < 16; ++sc) {
    const int s0 = sc * 64;
    __syncthreads();   // prev chunk's P reads of Kt + PV reads of Vt/pT complete
    {  // stage K tile 64s x 128e (k1's Kt pattern, 64 rows)
      const int r = t >> 2, c = (t & 3) * 32;
      const u16* src = kb + (size_t)(bx * L + s0 + r) * E + c;
#pragma unroll
      for (int i = 0; i < 4; ++i)
        *(uint4*)&Kt[r][c + i * 8] = *(const uint4*)(src + i * 8);
    }
    {  // stage V^T tile 128e x 64s (k34's 64-wide Vt pattern)
      const int e = t >> 1, off = (t & 1) * 32;
      const u16* src = vt + ((size_t)(by * E + e)) * L + s0 + off;
#pragma unroll
      for (int i = 0; i < 4; ++i)
        *(uint4*)&Vt[e][off + i * 8] = *(const uint4*)(src + i * 8);
    }
    __syncthreads();
    // P = exp(QK^T * SCALE): out row l0+lw*16+quad*4+r, col ks*32+mt*16+col
#pragma unroll
    for (int ks = 0; ks < 2; ++ks) {
      floatx4 sf = (floatx4){0.f, 0.f, 0.f, 0.f};
#pragma unroll
      for (int k = 0; k < 4; ++k) {
        bf16frag bkf = *(const bf16frag*)&Kt[ks * 32 + mt * 16 + col][k * 32 + quad * 8];
        sf = __builtin_amdgcn_mfma_f32_16x16x32_bf16(af[k], bkf, sf, 0, 0, 0);
      }
#pragma unroll
      for (int r = 0; r < 4; ++r) {
        float pexp = __expf(sf[r] * SCALE);
        rs[r] += pexp;
        pT[lw * 16 + quad * 4 + r][ks * 32 + mt * 16 + col] = bfr(pexp);
      }
    }
    __syncthreads();
    // PV accumulate (k34's inner loop, pT as A)
#pragma unroll
    for (int ks = 0; ks < 2; ++ks) {
      bf16frag pf = *(const bf16frag*)&pT[lw * 16 + col][ks * 32 + quad * 8];
#pragma unroll
      for (int i = 0; i < 4; ++i) {
        bf16frag rf = *(const bf16frag*)&Vt[(eg * 4 + i) * 16 + col][ks * 32 + quad * 8];
        vf[i] = __builtin_amdgcn_mfma_f32_16x16x32_bf16(pf, rf, vf[i], 0, 0, 0);
      }
    }
  }
  // rowsum reduce: 16 col-lanes via shfl, then across mt wave pairs via LDS (k1 clone)
#pragma unroll
  for (int m = 1; m <= 8; m <<= 1)
#pragma unroll
    for (int r = 0; r < 4; ++r) rs[r] += __shfl_xor(rs[r], m, 64);
  __syncthreads();
  if (col == 0)
#pragma unroll
    for (int r = 0; r < 4; ++r) red[w * 16 + quad * 4 + r] = rs[r];
  __syncthreads();
  if (mt == 0 && col == 0)
#pragma unroll
    for (int r = 0; r < 4; ++r) {
      const float s = red[(lw * 2) * 16 + quad * 4 + r] + red[(lw * 2 + 1) * 16 + quad * 4 + r];
      inv_l[lw * 16 + quad * 4 + r] = 1.0f / s;
    }
  __syncthreads();
  float is[4];
#pragma unroll
  for (int r = 0; r < 4; ++r) is[r] = inv_l[lw * 16 + quad * 4 + r];
  // Rt overlay on Kt region (all Kt reads finished >=2 barriers ago)
#pragma unroll
  for (int i = 0; i < 4; ++i)
#pragma unroll
    for (int r = 0; r < 4; ++r)
      Rt[lw * 16 + quad * 4 + r][(eg * 4 + i) * 16 + col] = vf[i][r] * is[r];
  __syncthreads();
  if (p == 0) {
    // x==0: series==1 -> V[b,l,e,0] = sum over this tile's rows (stage-2 m) of R
    if (t < 128) {
      float ssum = 0.f;
#pragma unroll
      for (int r = 0; r < 32; ++r) ssum += Rt[r][t];
      atomicAdd(&colsum[b * 128 + t], ssum);
    }
    return;
  }
  const int cslot = b * 9 + (p - 1);
  // ---- Phase B1: kp = R . Wk^T + bk via MFMA (A from Rt, B from pre-packed wkf)
  bf16frag aR[4];
#pragma unroll
  for (int k = 0; k < 4; ++k) {
    u16 us[8];
#pragma unroll
    for (int j = 0; j < 8; ++j) us[j] = bfr(Rt[lw * 16 + col][k * 32 + quad * 8 + j]);
    aR[k] = *(bf16frag*)us;
  }
#pragma unroll
  for (int ft = 0; ft < 4; ++ft) {
    const int f0 = (eg * 4 + ft) * 16;
    floatx4 c = (floatx4){0.f, 0.f, 0.f, 0.f};
#pragma unroll
    for (int k = 0; k < 4; ++k) {
      bf16frag bf = *(const bf16frag*)&wkf[(size_t)((((eg * 4 + ft) * 4 + k) * 64) + lane) * 8];
      c = __builtin_amdgcn_mfma_f32_16x16x32_bf16(aR[k], bf, c, 0, 0, 0);
    }
    const float bias = bk[f0 + col];
#pragma unroll
    for (int r = 0; r < 4; ++r)
      kp_bf[((size_t)(cslot * L + l0 + lw * 16 + quad * 4 + r)) * E + f0 + col] =
          bfr(c[r] + bias);
  }
  // ---- Phase B2: rt_bf[cslot][e][l] = bf16(R^T) from Rt
  {
    const int e = t >> 1, half = t & 1;
    u16 us[16];
#pragma unroll
    for (int j = 0; j < 16; ++j) us[j] = bfr(Rt[half * 16 + j][e]);
    u16* dst = rt_bf + ((size_t)(cslot * E + e)) * L + l0 + half * 16;
    *(uint4*)dst = *(uint4*)&us[0];
    *(uint4*)(dst + 8) = *(uint4*)&us[8];
  }
}

// ---------------- K5: fused stage 2, templated NY, phase-local staging --------------
// (unchanged from the verified round-8 kernel: 44.8 us, grid 1536)
template<int NY>
static __device__ __forceinline__ void k5_body(const float* __restrict__ qp,
                                               const u16* __restrict__ kp_bf,
                                               const u16* __restrict__ rt_bf,
                                               float* __restrict__ vws,
                                               u16 (*__restrict__ uni)[128][40],
                                               u16 (*__restrict__ pT)[32][40],
                                               const int t, const int b,
                                               const int lt, const int part,
                                               const int slotbase) {
  constexpr int x = NY - 1;                       // 1..3, compile-time
  u16 (*kpT)[32][136] = (u16 (*)[32][136])uni;    // kpT overlays rtT region
  const int mc0 = part * 4;
  const int l0 = lt * 32;
  const int lane = t & 63, w = t >> 6;
  const int col = lane & 15, quad = lane >> 4;
  const int lw = w >> 1, mt = w & 1, eg = w & 1;
  const int smr = t >> 3, se0 = (t & 7) * 16;   // kp staging: m-row, u16 col offset
  const int sre = t >> 1, srh = (t & 1) * 16;   // rt staging: e-row, u16 m offset

  // A-frags converted directly from global qp (fp32 -> bf16), no LDS round-trip
  bf16frag af[4];
  {
    const float* qpr = qp + ((size_t)((b * L + l0 + lw * 16 + col) * X + x)) * E;
#pragma unroll
    for (int k = 0; k < 4; ++k) {
      float4 v0 = *(const float4*)(qpr + k * 32 + quad * 8);
      float4 v1 = *(const float4*)(qpr + k * 32 + quad * 8 + 4);
      u16 us[8] = {bfr(v0.x), bfr(v0.y), bfr(v0.z), bfr(v0.w),
                   bfr(v1.x), bfr(v1.y), bfr(v1.z), bfr(v1.w)};
      af[k] = *(bf16frag*)us;
    }
  }
  floatx4 vf[4];
#pragma unroll
  for (int i = 0; i < 4; ++i) vf[i] = (floatx4){0.f, 0.f, 0.f, 0.f};

  for (int mc = mc0; mc < mc0 + 4; ++mc) {
    const int m0 = mc * 32;
    __syncthreads();   // prev chunk's PV reads of uni & pT complete
#pragma unroll
    for (int y = 0; y < NY; ++y) {   // stage ALL NY kp tiles (phase-local regs)
      const u16* src = kp_bf + ((size_t)(slotbase + y) * L + m0 + smr) * E + se0;
      uint4 a0 = *(const uint4*)src;
      uint4 a1 = *(const uint4*)(src + 8);
      *(uint4*)&kpT[y][smr][se0] = a0;
      *(uint4*)&kpT[y][smr][se0 + 8] = a1;
    }
    __syncthreads();
    floatx4 sf[NY];
#pragma unroll
    for (int y = 0; y < NY; ++y) sf[y] = (floatx4){0.f, 0.f, 0.f, 0.f};
#pragma unroll
    for (int y = 0; y < NY; ++y)
#pragma unroll
      for (int k = 0; k < 4; ++k) {
        bf16frag bkf = *(const bf16frag*)&kpT[y][mt * 16 + col][k * 32 + quad * 8];
        sf[y] = __builtin_amdgcn_mfma_f32_16x16x32_bf16(af[k], bkf, sf[y], 0, 0, 0);
      }
    // softmax over y (lane-local, NY>=2 terms)
    u16 pu[NY][4];
#pragma unroll
    for (int r = 0; r < 4; ++r) {
      float zz[NY]; float mx = -3.4e38f;
#pragma unroll
      for (int y = 0; y < NY; ++y) { zz[y] = sf[y][r] * SCALE; mx = fmaxf(mx, zz[y]); }
      float sum = 0.f;
#pragma unroll
      for (int y = 0; y < NY; ++y) { zz[y] = __expf(zz[y] - mx); sum += zz[y]; }
      float inv = 1.0f / sum;
#pragma unroll
      for (int y = 0; y < NY; ++y) pu[y][r] = bfr(zz[y] * inv);
    }
    __syncthreads();   // score ds_reads of kpT done -> safe to overlay rtT
#pragma unroll
    for (int y = 0; y < NY; ++y) {
#pragma unroll
      for (int r = 0; r < 4; ++r)
        pT[y][lw * 16 + quad * 4 + r][mt * 16 + col] = pu[y][r];
      const u16* src = rt_bf + ((size_t)(slotbase + y) * E + sre) * L + m0 + srh;
      uint4 a0 = *(const uint4*)src;
      uint4 a1 = *(const uint4*)(src + 8);
      *(uint4*)&uni[y][sre][srh] = a0;
      *(uint4*)&uni[y][sre][srh + 8] = a1;
    }
    __syncthreads();
#pragma unroll
    for (int y = 0; y < NY; ++y) {
      bf16frag pf = *(const bf16frag*)&pT[y][lw * 16 + col][quad * 8];
#pragma unroll
      for (int i = 0; i < 4; ++i) {
        bf16frag rf = *(const bf16frag*)&uni[y][(eg * 4 + i) * 16 + col][quad * 8];
        vf[i] = __builtin_amdgcn_mfma_f32_16x16x32_bf16(pf, rf, vf[i], 0, 0, 0);
      }
    }
  }
  // dense per-(b,x,part) vws slot; every read slot is written (no poison reliance)
  float* dst = vws + (size_t)(b * 24 + (x - 1) * 8 + part) * (L * E) + (size_t)l0 * E;
#pragma unroll
  for (int i = 0; i < 4; ++i)
#pragma unroll
    for (int r = 0; r < 4; ++r)
      dst[((size_t)(lw * 16 + quad * 4 + r)) * E + (eg * 4 + i) * 16 + col] = vf[i][r];
}

__global__ __launch_bounds__(256) void k5_stage2(const float* __restrict__ qp,
                                                 const u16* __restrict__ kp_bf,
                                                 const u16* __restrict__ rt_bf,
                                                 float* __restrict__ vws) {
  __shared__ __align__(16) u16 uni[4][128][40];   // 40960 B: rtT (PV); kpT overlays
  __shared__ __align__(16) u16 pT[4][32][40];     // 10240 B
  const int t = threadIdx.x;
  // XCD-chunked bijection (1536 = 8*192), (b,x)-major virtual order for L2 locality.
  const int vb = (blockIdx.x & 7) * 192 + (blockIdx.x >> 3);
  const int g = vb >> 8;            // 0..5 = b*3 + (x-1)
  const int r = vb & 255;
  const int b = g / 3, xm1 = g % 3;
  const int part = r >> 5, lt = r & 31;
  const int slotbase = b * 9 + ((xm1 == 0) ? 0 : (xm1 == 1) ? 2 : 5);
  if (xm1 == 0)      k5_body<2>(qp, kp_bf, rt_bf, vws, uni, pT, t, b, lt, part, slotbase);
  else if (xm1 == 1) k5_body<3>(qp, kp_bf, rt_bf, vws, uni, pT, t, b, lt, part, slotbase);
  else               k5_body<4>(qp, kp_bf, rt_bf, vws, uni, pT, t, b, lt, part, slotbase);
}

// ---------------- K6: 8 (b,l) rows per block; coalesced wv4t; LDS-broadcast rows ----
__global__ __launch_bounds__(256) void k6_vout(const float* __restrict__ vws,
                                               const float4* __restrict__ wv4t,
                                               const float* __restrict__ bv,
                                               const float* __restrict__ colsum,
                                               float* __restrict__ vout) {
  __shared__ __align__(16) float rowf[8][512];   // [l8][e*4+x] = V[b,l0+l8,e,x], 16 KB
  const int t = threadIdx.x;
  const int blk = blockIdx.x;          // 256 blocks, 8 consecutive (b,l) each
  const int bl0 = blk * 8;
  const int b = bl0 >> 10;
  const int lbase = bl0 & 1023;
  {
    const int o = t * 2;
    const int xh = o >> 7, e = o & 127;   // xh wave-uniform (64 threads per xh)
    if (xh == 0) {
      const float sx = colsum[b * 128 + e];
      const float sy = colsum[b * 128 + e + 1];
#pragma unroll
      for (int l8 = 0; l8 < 8; ++l8) {
        rowf[l8][e * 4] = sx;
        rowf[l8][(e + 1) * 4] = sy;
      }
    } else {
      const size_t pbase = (size_t)(b * 24 + (xh - 1) * 8) * 131072;
#pragma unroll
      for (int l8 = 0; l8 < 8; ++l8) {
        const size_t base = pbase + (size_t)(lbase + l8) * 128 + e;
        float sx = 0.f, sy = 0.f;
#pragma unroll
        for (int p = 0; p < 8; ++p) {
          float2 v = *(const float2*)(vws + base + (size_t)p * 131072);
          sx += v.x; sy += v.y;
        }
        rowf[l8][e * 4 + xh] = sx;
        rowf[l8][(e + 1) * 4 + xh] = sy;
      }
    }
  }
  __syncthreads();
#pragma unroll
  for (int rep = 0; rep < 2; ++rep) {
    const int o = t + rep * 256;
    const int s = o >> 7, f = o & 127;   // s wave-uniform; f = lane (coalesced)
    float acc[8] = {0.f, 0.f, 0.f, 0.f, 0.f, 0.f, 0.f, 0.f};
    const float4* wp = wv4t + f;
#pragma unroll 4
    for (int e4 = 0; e4 < 32; ++e4) {
      const float4 wv = wp[e4 * 128];
#pragma unroll
      for (int l8 = 0; l8 < 8; ++l8) {
        const float4 rv = *(const float4*)&rowf[l8][(s * 32 + e4) * 4];
        acc[l8] += wv.x * rv.x + wv.y * rv.y + wv.z * rv.z + wv.w * rv.w;
      }
    }
    const float bb = bv[f];
#pragma unroll
    for (int l8 = 0; l8 < 8; ++l8)
      vout[(size_t)(bl0 + l8) * 512 + s * 128 + f] = acc[l8] + bb;
  }
}

extern "C" void kernel_launch(void* const* d_in, const int* in_sizes, int n_in,
                              void* d_out, int out_size, void* d_ws, size_t ws_size,
                              hipStream_t stream) {
  const float* q     = (const float*)d_in[1];
  const float* key   = (const float*)d_in[2];
  const float* value = (const float*)d_in[3];
  const float* sigma = (const float*)d_in[4];
  const float* qp    = (const float*)d_in[8];
  const float* Wk    = (const float*)d_in[9];
  const float* bk    = (const float*)d_in[10];
  const float* Wv    = (const float*)d_in[11];
  const float* bv    = (const float*)d_in[12];

  float* out    = (float*)d_out;
  float* Vout   = out;
  float* sout   = out + 1048576;
  float* prior  = out + 9437184;
  float* sigout = out + 17825792;

  // ws layout (float-unit offsets), peak 10,748,160 floats = 43.0 MB. Lifetimes
  // (launch order k_prep,k134,k5,k6). sbh is GONE (k134 fuses k1+k34):
  //  qkb   [4,194,304, 5,242,880)  u16[2M]    prep w, k134 r (qb 1M, kb 1M u16)
  //  vt    [5,242,880, 5,767,168)  u16[1M]    prep w, k134 r
  //  wv4t  [6,291,456, 6,307,840)  f32[16K]   prep w, k6 r
  //  wkf   [6,307,840, 6,316,032)  u16[16K]   prep w, k134 r (B-frag-packed Wk)
  //  kp_bf [8,388,608, 9,568,256)  u16[2.36M] k134 w, k5 r  (18 y<=x, x>=1 slots)
  //  rt_bf [9,568,256, 10,747,904) u16[2.36M] k134 w, k5 r  (disjoint from kp_bf)
  //  colsum[10,747,904, +256)      f32        prep zero, k134 atomicAdd, k6 r
  //  vws   [0, 6,291,456)          f32        k5 w, k6 r  (48 slots of 131072;
  //                                overlays qkb/vt, dead after k134)
  float* ws     = (float*)d_ws;
  u16*   qb     = (u16*)(ws + 4194304);
  u16*   kb     = qb + 1048576;
  u16*   vt     = (u16*)(ws + 5242880);
  float* wv4t   = ws + 6291456;
  u16*   wkf    = (u16*)(ws + 6307840);
  u16*   kp_bf  = (u16*)(ws + 8388608);
  u16*   rt_bf  = (u16*)(ws + 9568256);
  float* colsum = ws + 10747904;
  float* vws    = ws;

  hipLaunchKernelGGL(k_prep,     dim3(17560), dim3(256), 0, stream, q, key, value, sigma,
                     Wv, Wk, (float4*)sout, (u16*)qb, colsum, vt, (float4*)wv4t, wkf, prior, sigout);
  hipLaunchKernelGGL(k134_fused, dim3(640),  dim3(256), 0, stream, qb, kb, vt, wkf, bk, kp_bf, rt_bf, colsum);
  hipLaunchKernelGGL(k5_stage2,  dim3(1536), dim3(256), 0, stream, qp, kp_bf, rt_bf, vws);
  hipLaunchKernelGGL(k6_vout,    dim3(256),  dim3(256), 0, stream, vws, (const float4*)wv4t, bv, colsum, Vout);
}

// Round 10
// 202.764 us; speedup vs baseline: 1.0559x; 1.0559x over previous
//
#include <hip/hip_runtime.h>
#include <math.h>

#define B 2
#define L 1024
#define X 4
#define E 128
#define Y 4
#define SCALE 0.08838834764831845f  // 1/sqrt(128)

typedef unsigned short u16;
typedef __attribute__((ext_vector_type(8))) short bf16frag;   // 8 bf16 (4 VGPRs)
typedef __attribute__((ext_vector_type(4))) float floatx4;    // 4 fp32 acc

// round-to-nearest-even f32 -> bf16
static __device__ __forceinline__ u16 bfr(float f) {
  union { float f; unsigned u; } c; c.f = f;
  unsigned r = (c.u + 0x7fffu + ((c.u >> 16) & 1u)) >> 16;
  return (u16)r;
}

// ---------------- K_PREP: fused {series fill, Wv transpose, q/k bf16 convert, ------
// V transpose, Gaussian prior, Wk fragment-pack}. Branch is block-uniform.
// Ranges: [0,8192) fill | [8192,8208) wvt | [8208,9232) qk conv | [9232,9360) vtrans
//         | [9360,17552) prior | [17552,17560) wk-frag.
__global__ __launch_bounds__(256) void k_prep(const float* __restrict__ q,
                                              const float* __restrict__ key,
                                              const float* __restrict__ value,
                                              const float* __restrict__ sigma,
                                              const float* __restrict__ Wv,
                                              const float* __restrict__ Wk,
                                              float4* __restrict__ sout4,
                                              u16* __restrict__ qkb,
                                              float* __restrict__ colsum,
                                              u16* __restrict__ vt,
                                              float4* __restrict__ wv4t,
                                              u16* __restrict__ wkf,
                                              float* __restrict__ prior,
                                              float* __restrict__ sigout) {
  __shared__ float shp[2];   // prior branch only: {coef, inv2s2}
  const int bid = blockIdx.x;
  const int t = threadIdx.x;
  if (bid < 8192) {
    // series_out is identically 0.25 (mean over the softmax axis)
    sout4[bid * 256 + t] = make_float4(0.25f, 0.25f, 0.25f, 0.25f);
  } else if (bid < 8208) {
    // wv4t[e4*128+f] = float4{Wv[f][4e4..4e4+3]} (kills k6's 64-line gather)
    const int idx = (bid - 8192) * 256 + t;
    const int e4 = idx >> 7, f = idx & 127;
    wv4t[idx] = *(const float4*)(Wv + f * E + e4 * 4);
  } else if (bid < 9232) {
    // q,key fp32 [b,l,x,e] -> bf16 [bx][l][e]; zero colsum
    if (bid == 8208) colsum[t] = 0.f;
    const int f = (bid - 8208) * 256 + t;   // 262144 total
    const int row = f >> 4, c8 = (f & 15) * 8;
    const int sel = row >> 13, row2 = row & 8191;   // row2 = b*4096 + l*4 + x
    const int b = row2 >> 12, l = (row2 >> 2) & 1023, x = row2 & 3;
    const float* src = (sel ? key : q) + (size_t)row2 * E + c8;
    float4 v0 = *(const float4*)src;
    float4 v1 = *(const float4*)(src + 4);
    u16 us[8] = {bfr(v0.x), bfr(v0.y), bfr(v0.z), bfr(v0.w),
                 bfr(v1.x), bfr(v1.y), bfr(v1.z), bfr(v1.w)};
    u16* dst = qkb + (size_t)(sel * 8192 + (b * 4 + x) * 1024 + l) * E + c8;
    *(uint4*)dst = *(uint4*)us;
  } else if (bid < 9360) {
    // vt[(b*4+y)*128+e][s] = bf16(value[b,s,y,e]); 128 blocks x 256 thr
    const int blk = bid - 9232;
    const int by = blk >> 4, sc2 = blk & 15;
    const int b = by >> 2, y = by & 3;
    const int e = t & 127, sh = t >> 7;
    const int s0 = sc2 * 64 + sh * 32;
    u16 us[32];
#pragma unroll 8
    for (int ss = 0; ss < 32; ++ss)
      us[ss] = bfr(value[((size_t)((b * L + s0 + ss) * Y + y)) * E + e]);
    u16* dst = vt + ((size_t)(by * E + e)) * L + s0;
#pragma unroll
    for (int i = 0; i < 4; ++i) *(uint4*)(dst + i * 8) = *(uint4*)&us[i * 8];
  } else if (bid < 17552) {
    // Gaussian prior + sig output. f64 sigma chain computed ONCE per block,
    // broadcast via LDS.
    const int row = bid - 9360;
    const int bx = row >> 10;
    const int i = row & 1023;
    const int b = bx >> 2, x = bx & 3;
    if (t == 0) {
      const double sv = (double)sigma[((size_t)(b * L + i)) * X + x];
      const double sg = 1.0 / (1.0 + exp(-5.0 * sv)) + 1e-5;
      const double s3 = exp(sg * 1.0986122886681098) - 1.0;
      shp[0] = (float)(1.0 / (2.5066282746310002 * s3));
      shp[1] = (float)(0.5 / (s3 * s3));
      sigout[row] = (float)s3;
    }
    __syncthreads();
    const float coef = shp[0], inv2s2 = shp[1];
    const float di = (float)i;
    const int j0 = t * 4;
    float4 o; float d;
    d = di - (float)(j0 + 0); o.x = coef * __expf(-d * d * inv2s2);
    d = di - (float)(j0 + 1); o.y = coef * __expf(-d * d * inv2s2);
    d = di - (float)(j0 + 2); o.z = coef * __expf(-d * d * inv2s2);
    d = di - (float)(j0 + 3); o.w = coef * __expf(-d * d * inv2s2);
    *(float4*)(prior + (size_t)row * 1024 + j0) = o;
  } else {
    // wkf: Wk packed in MFMA-B-fragment order so k34's B1 loads are coalesced.
    const int idx = (bid - 17552) * 256 + t;   // [0,2048)
    const int slot = idx >> 6, lane2 = idx & 63;
    const int col = lane2 & 15, quad = lane2 >> 4;
    const int eg = slot >> 4, ft = (slot >> 2) & 3, k = slot & 3;
    const float* src = Wk + (size_t)((eg * 4 + ft) * 16 + col) * E + k * 32 + quad * 8;
    float4 w0 = *(const float4*)src;
    float4 w1 = *(const float4*)(src + 4);
    u16 us[8] = {bfr(w0.x), bfr(w0.y), bfr(w0.z), bfr(w0.w),
                 bfr(w1.x), bfr(w1.y), bfr(w1.z), bfr(w1.w)};
    *(uint4*)(wkf + (size_t)idx * 8) = *(uint4*)us;
  }
}

// ---------------- K1: MFMA QK^T, SINGLE-pass (no max: |score| <= ~6, exp safe) ------
// Writes unnormalized exp(score) bf16 P + isum = 1/rowsum. k34 folds normalization in.
__global__ __launch_bounds__(512) void k1_mfma(const u16* __restrict__ qb,
                                               const u16* __restrict__ kb,
                                               u16* __restrict__ sbh,
                                               float* __restrict__ isum) {
  __shared__ __align__(16) u16 Qt[16][136];
  __shared__ __align__(16) u16 Kt[128][136];
  __shared__ float red[8][16];
  const int t = threadIdx.x;
  const int blk = blockIdx.x;
  const int lt = blk & 63, bx = blk >> 6;
  const int l0 = lt * 16;
  const int lane = t & 63, w = t >> 6;
  const int col = lane & 15, quad = lane >> 4;
  if (t < 256) {
    const int r = t >> 4, c8 = (t & 15) * 8;
    *(uint4*)&Qt[r][c8] = *(const uint4*)(qb + (size_t)(bx * L + l0 + r) * E + c8);
  }
  __syncthreads();
  bf16frag af[4];
#pragma unroll
  for (int k = 0; k < 4; ++k)
    af[k] = *(const bf16frag*)&Qt[col][k * 32 + quad * 8];

  float rs[4] = {0.f, 0.f, 0.f, 0.f};
  for (int sc = 0; sc < 8; ++sc) {
    __syncthreads();
    {
      const int r = t >> 2, c = (t & 3) * 32;
      const u16* src = kb + (size_t)(bx * L + sc * 128 + r) * E + c;
#pragma unroll
      for (int i = 0; i < 4; ++i)
        *(uint4*)&Kt[r][c + i * 8] = *(const uint4*)(src + i * 8);
    }
    __syncthreads();
    floatx4 acc = (floatx4){0.f, 0.f, 0.f, 0.f};
#pragma unroll
    for (int k = 0; k < 4; ++k) {
      bf16frag bk = *(const bf16frag*)&Kt[w * 16 + col][k * 32 + quad * 8];
      acc = __builtin_amdgcn_mfma_f32_16x16x32_bf16(af[k], bk, acc, 0, 0, 0);
    }
    const size_t so = (size_t)sc * 128 + w * 16 + col;
#pragma unroll
    for (int r = 0; r < 4; ++r) {
      float p = __expf(acc[r] * SCALE);
      rs[r] += p;
      sbh[(size_t)(bx * L + l0 + quad * 4 + r) * L + so] = bfr(p);
    }
  }
#pragma unroll
  for (int m = 1; m <= 8; m <<= 1)
#pragma unroll
    for (int r = 0; r < 4; ++r) rs[r] += __shfl_xor(rs[r], m, 64);
  __syncthreads();
  if (col == 0)
#pragma unroll
    for (int r = 0; r < 4; ++r) red[w][quad * 4 + r] = rs[r];
  __syncthreads();
  if (w == 0 && col == 0)
#pragma unroll
    for (int r = 0; r < 4; ++r) {
      float s = 0.f;
#pragma unroll
      for (int j = 0; j < 8; ++j) s += red[j][quad * 4 + r];
      isum[bx * L + l0 + quad * 4 + r] = 1.0f / s;
    }
}

// ---------------- K34: fused Retr (MFMA) + Wk projection (MFMA) + transposes --------
// y<=x ONLY; p==0 (x=0) -> colsum. 64-wide s-tiles. B1 reads pre-packed wkf
// (coalesced 16B/lane).
__global__ __launch_bounds__(256) void k34_retr_kp(const u16* __restrict__ sbh,
                                                   const u16* __restrict__ vt,
                                                   const float* __restrict__ isum,
                                                   const u16* __restrict__ wkf,
                                                   const float* __restrict__ bk,
                                                   u16* __restrict__ kp_bf,
                                                   u16* __restrict__ rt_bf,
                                                   float* __restrict__ colsum) {
  __shared__ __align__(16) unsigned char smem[23040];  // Pt 4608 + Vt 18432
  u16 (*Pt)[72] = (u16(*)[72])smem;                // 32x72 u16 (4608 B)
  u16 (*Vt)[72] = (u16(*)[72])(smem + 4608);       // 128x72 u16 (18432 B)
  float (*Rt)[132] = (float(*)[132])smem;          // 32x132 f32 (16896 B), overlay
  const int t = threadIdx.x;
  const int blk = (blockIdx.x & 7) * 80 + (blockIdx.x >> 3);  // bijective, 640=8*80
  const int lt = blk & 31;
  const int cp = blk >> 5;                     // [0,20) = b*10 + p
  const int b = cp / 10, p = cp % 10;
  const int x = (p >= 6) ? 3 : (p >= 3) ? 2 : (p >= 1) ? 1 : 0;
  const int y = p - ((x * (x + 1)) >> 1);
  const int by = b * 4 + y;                    // vt batch
  const int srow = (b * 4 + x) * L;            // Search batch row base
  const int l0 = lt * 32;
  const int lane = t & 63, w = t >> 6;
  const int col = lane & 15, quad = lane >> 4;
  const int lw = w >> 1, eg = w & 1;
  floatx4 vf[4];
#pragma unroll
  for (int i = 0; i < 4; ++i) vf[i] = (floatx4){0.f, 0.f, 0.f, 0.f};
  for (int sc2 = 0; sc2 < 16; ++sc2) {
    const int s0 = sc2 * 64;
    __syncthreads();
    {  // stage P tile 32l x 64s (4 KB: 256 thr x 16 B)
      const int r = t >> 3, c8 = (t & 7) * 8;
      *(uint4*)&Pt[r][c8] = *(const uint4*)(sbh + (size_t)(srow + l0 + r) * L + s0 + c8);
    }
    {  // stage V^T tile 128e x 64s (16 KB: 256 thr x 64 B)
      const int e = t >> 1, off = (t & 1) * 32;
      const u16* src = vt + ((size_t)(by * E + e)) * L + s0 + off;
#pragma unroll
      for (int i = 0; i < 4; ++i)
        *(uint4*)&Vt[e][off + i * 8] = *(const uint4*)(src + i * 8);
    }
    __syncthreads();
#pragma unroll
    for (int ks = 0; ks < 2; ++ks) {
      bf16frag pf = *(const bf16frag*)&Pt[lw * 16 + col][ks * 32 + quad * 8];
#pragma unroll
      for (int i = 0; i < 4; ++i) {
        bf16frag rf = *(const bf16frag*)&Vt[(eg * 4 + i) * 16 + col][ks * 32 + quad * 8];
        vf[i] = __builtin_amdgcn_mfma_f32_16x16x32_bf16(pf, rf, vf[i], 0, 0, 0);
      }
    }
  }
  float is[4];
#pragma unroll
  for (int r = 0; r < 4; ++r) is[r] = isum[srow + l0 + lw * 16 + quad * 4 + r];
  __syncthreads();  // all Pt/Vt reads done; smem becomes Rt
#pragma unroll
  for (int i = 0; i < 4; ++i)
#pragma unroll
    for (int r = 0; r < 4; ++r)
      Rt[lw * 16 + quad * 4 + r][(eg * 4 + i) * 16 + col] = vf[i][r] * is[r];
  __syncthreads();
  if (p == 0) {
    // x==0: softmax over the single unmasked y is 1 -> V[b,l,e,0] = sum_s R[s,e]
    if (t < 128) {
      float ssum = 0.f;
#pragma unroll
      for (int r = 0; r < 32; ++r) ssum += Rt[r][t];
      atomicAdd(&colsum[b * 128 + t], ssum);
    }
    return;
  }
  const int cslot = b * 9 + (p - 1);
  // ---- Phase B1: kp = R . Wk^T + bk via MFMA (A from Rt, B from pre-packed wkf)
  bf16frag aR[4];
#pragma unroll
  for (int k = 0; k < 4; ++k) {
    u16 us[8];
#pragma unroll
    for (int j = 0; j < 8; ++j) us[j] = bfr(Rt[lw * 16 + col][k * 32 + quad * 8 + j]);
    aR[k] = *(bf16frag*)us;
  }
#pragma unroll
  for (int ft = 0; ft < 4; ++ft) {
    const int f0 = (eg * 4 + ft) * 16;
    floatx4 c = (floatx4){0.f, 0.f, 0.f, 0.f};
#pragma unroll
    for (int k = 0; k < 4; ++k) {
      bf16frag bf = *(const bf16frag*)&wkf[(size_t)((((eg * 4 + ft) * 4 + k) * 64) + lane) * 8];
      c = __builtin_amdgcn_mfma_f32_16x16x32_bf16(aR[k], bf, c, 0, 0, 0);
    }
    const float bias = bk[f0 + col];
#pragma unroll
    for (int r = 0; r < 4; ++r)
      kp_bf[((size_t)(cslot * L + l0 + lw * 16 + quad * 4 + r)) * E + f0 + col] =
          bfr(c[r] + bias);
  }
  // ---- Phase B2: rt_bf[cslot][e][l] = bf16(R^T) from Rt
  {
    const int e = t >> 1, half = t & 1;
    u16 us[16];
#pragma unroll
    for (int j = 0; j < 16; ++j) us[j] = bfr(Rt[half * 16 + j][e]);
    u16* dst = rt_bf + ((size_t)(cslot * E + e)) * L + l0 + half * 16;
    *(uint4*)dst = *(uint4*)&us[0];
    *(uint4*)(dst + 8) = *(uint4*)&us[8];
  }
}

// ---------------- K5: fused stage 2, templated NY, phase-local staging --------------
// (unchanged from the verified round-8 kernel: 44.8 us, grid 1536)
template<int NY>
static __device__ __forceinline__ void k5_body(const float* __restrict__ qp,
                                               const u16* __restrict__ kp_bf,
                                               const u16* __restrict__ rt_bf,
                                               float* __restrict__ vws,
                                               u16 (*__restrict__ uni)[128][40],
                                               u16 (*__restrict__ pT)[32][40],
                                               const int t, const int b,
                                               const int lt, const int part,
                                               const int slotbase) {
  constexpr int x = NY - 1;                       // 1..3, compile-time
  u16 (*kpT)[32][136] = (u16 (*)[32][136])uni;    // kpT overlays rtT region
  const int mc0 = part * 4;
  const int l0 = lt * 32;
  const int lane = t & 63, w = t >> 6;
  const int col = lane & 15, quad = lane >> 4;
  const int lw = w >> 1, mt = w & 1, eg = w & 1;
  const int smr = t >> 3, se0 = (t & 7) * 16;   // kp staging: m-row, u16 col offset
  const int sre = t >> 1, srh = (t & 1) * 16;   // rt staging: e-row, u16 m offset

  // A-frags converted directly from global qp (fp32 -> bf16), no LDS round-trip
  bf16frag af[4];
  {
    const float* qpr = qp + ((size_t)((b * L + l0 + lw * 16 + col) * X + x)) * E;
#pragma unroll
    for (int k = 0; k < 4; ++k) {
      float4 v0 = *(const float4*)(qpr + k * 32 + quad * 8);
      float4 v1 = *(const float4*)(qpr + k * 32 + quad * 8 + 4);
      u16 us[8] = {bfr(v0.x), bfr(v0.y), bfr(v0.z), bfr(v0.w),
                   bfr(v1.x), bfr(v1.y), bfr(v1.z), bfr(v1.w)};
      af[k] = *(bf16frag*)us;
    }
  }
  floatx4 vf[4];
#pragma unroll
  for (int i = 0; i < 4; ++i) vf[i] = (floatx4){0.f, 0.f, 0.f, 0.f};

  for (int mc = mc0; mc < mc0 + 4; ++mc) {
    const int m0 = mc * 32;
    __syncthreads();   // prev chunk's PV reads of uni & pT complete
#pragma unroll
    for (int y = 0; y < NY; ++y) {   // stage ALL NY kp tiles (phase-local regs)
      const u16* src = kp_bf + ((size_t)(slotbase + y) * L + m0 + smr) * E + se0;
      uint4 a0 = *(const uint4*)src;
      uint4 a1 = *(const uint4*)(src + 8);
      *(uint4*)&kpT[y][smr][se0] = a0;
      *(uint4*)&kpT[y][smr][se0 + 8] = a1;
    }
    __syncthreads();
    floatx4 sf[NY];
#pragma unroll
    for (int y = 0; y < NY; ++y) sf[y] = (floatx4){0.f, 0.f, 0.f, 0.f};
#pragma unroll
    for (int y = 0; y < NY; ++y)
#pragma unroll
      for (int k = 0; k < 4; ++k) {
        bf16frag bkf = *(const bf16frag*)&kpT[y][mt * 16 + col][k * 32 + quad * 8];
        sf[y] = __builtin_amdgcn_mfma_f32_16x16x32_bf16(af[k], bkf, sf[y], 0, 0, 0);
      }
    // softmax over y (lane-local, NY>=2 terms)
    u16 pu[NY][4];
#pragma unroll
    for (int r = 0; r < 4; ++r) {
      float zz[NY]; float mx = -3.4e38f;
#pragma unroll
      for (int y = 0; y < NY; ++y) { zz[y] = sf[y][r] * SCALE; mx = fmaxf(mx, zz[y]); }
      float sum = 0.f;
#pragma unroll
      for (int y = 0; y < NY; ++y) { zz[y] = __expf(zz[y] - mx); sum += zz[y]; }
      float inv = 1.0f / sum;
#pragma unroll
      for (int y = 0; y < NY; ++y) pu[y][r] = bfr(zz[y] * inv);
    }
    __syncthreads();   // score ds_reads of kpT done -> safe to overlay rtT
#pragma unroll
    for (int y = 0; y < NY; ++y) {
#pragma unroll
      for (int r = 0; r < 4; ++r)
        pT[y][lw * 16 + quad * 4 + r][mt * 16 + col] = pu[y][r];
      const u16* src = rt_bf + ((size_t)(slotbase + y) * E + sre) * L + m0 + srh;
      uint4 a0 = *(const uint4*)src;
      uint4 a1 = *(const uint4*)(src + 8);
      *(uint4*)&uni[y][sre][srh] = a0;
      *(uint4*)&uni[y][sre][srh + 8] = a1;
    }
    __syncthreads();
#pragma unroll
    for (int y = 0; y < NY; ++y) {
      bf16frag pf = *(const bf16frag*)&pT[y][lw * 16 + col][quad * 8];
#pragma unroll
      for (int i = 0; i < 4; ++i) {
        bf16frag rf = *(const bf16frag*)&uni[y][(eg * 4 + i) * 16 + col][quad * 8];
        vf[i] = __builtin_amdgcn_mfma_f32_16x16x32_bf16(pf, rf, vf[i], 0, 0, 0);
      }
    }
  }
  // dense per-(b,x,part) vws slot; every read slot is written (no poison reliance)
  float* dst = vws + (size_t)(b * 24 + (x - 1) * 8 + part) * (L * E) + (size_t)l0 * E;
#pragma unroll
  for (int i = 0; i < 4; ++i)
#pragma unroll
    for (int r = 0; r < 4; ++r)
      dst[((size_t)(lw * 16 + quad * 4 + r)) * E + (eg * 4 + i) * 16 + col] = vf[i][r];
}

__global__ __launch_bounds__(256) void k5_stage2(const float* __restrict__ qp,
                                                 const u16* __restrict__ kp_bf,
                                                 const u16* __restrict__ rt_bf,
                                                 float* __restrict__ vws) {
  __shared__ __align__(16) u16 uni[4][128][40];   // 40960 B: rtT (PV); kpT overlays
  __shared__ __align__(16) u16 pT[4][32][40];     // 10240 B
  const int t = threadIdx.x;
  // XCD-chunked bijection (1536 = 8*192), (b,x)-major virtual order for L2 locality.
  const int vb = (blockIdx.x & 7) * 192 + (blockIdx.x >> 3);
  const int g = vb >> 8;            // 0..5 = b*3 + (x-1)
  const int r = vb & 255;
  const int b = g / 3, xm1 = g % 3;
  const int part = r >> 5, lt = r & 31;
  const int slotbase = b * 9 + ((xm1 == 0) ? 0 : (xm1 == 1) ? 2 : 5);
  if (xm1 == 0)      k5_body<2>(qp, kp_bf, rt_bf, vws, uni, pT, t, b, lt, part, slotbase);
  else if (xm1 == 1) k5_body<3>(qp, kp_bf, rt_bf, vws, uni, pT, t, b, lt, part, slotbase);
  else               k5_body<4>(qp, kp_bf, rt_bf, vws, uni, pT, t, b, lt, part, slotbase);
}

// ---------------- K6: re-parallelized -- 1024 blocks x 2 rows (was 256 x 8) ---------
// The round-3 rewrite fixed the Wv gather but cut the grid to 256 blocks = 1
// block/CU = 4 waves/CU: the 24 MB vws stream ran latency-starved. Now 4 KB LDS
// and 1024 blocks -> 4+ blocks/CU, 16+ waves/CU. Inner loop (coalesced wv4t,
// LDS-broadcast rows, static accs) unchanged.
__global__ __launch_bounds__(256) void k6_vout(const float* __restrict__ vws,
                                               const float4* __restrict__ wv4t,
                                               const float* __restrict__ bv,
                                               const float* __restrict__ colsum,
                                               float* __restrict__ vout) {
  __shared__ __align__(16) float rowf[2][512];   // [l2][e*4+x], 4 KB
  const int t = threadIdx.x;
  const int blk = blockIdx.x;          // 1024 blocks, 2 consecutive (b,l) each
  const int bl0 = blk * 2;
  const int b = bl0 >> 10;
  const int lbase = bl0 & 1023;
  {
    const int o = t * 2;
    const int xh = o >> 7, e = o & 127;   // xh wave-uniform (64 threads per xh)
    if (xh == 0) {
      const float sx = colsum[b * 128 + e];
      const float sy = colsum[b * 128 + e + 1];
#pragma unroll
      for (int l2 = 0; l2 < 2; ++l2) {
        rowf[l2][e * 4] = sx;
        rowf[l2][(e + 1) * 4] = sy;
      }
    } else {
      const size_t pbase = (size_t)(b * 24 + (xh - 1) * 8) * 131072;
#pragma unroll
      for (int l2 = 0; l2 < 2; ++l2) {
        const size_t base = pbase + (size_t)(lbase + l2) * 128 + e;
        float sx = 0.f, sy = 0.f;
#pragma unroll
        for (int p = 0; p < 8; ++p) {
          float2 v = *(const float2*)(vws + base + (size_t)p * 131072);
          sx += v.x; sy += v.y;
        }
        rowf[l2][e * 4 + xh] = sx;
        rowf[l2][(e + 1) * 4 + xh] = sy;
      }
    }
  }
  __syncthreads();
#pragma unroll
  for (int rep = 0; rep < 2; ++rep) {
    const int o = t + rep * 256;
    const int s = o >> 7, f = o & 127;   // s wave-uniform; f = lane (coalesced)
    float acc[2] = {0.f, 0.f};
    const float4* wp = wv4t + f;
#pragma unroll 4
    for (int e4 = 0; e4 < 32; ++e4) {
      const float4 wv = wp[e4 * 128];
#pragma unroll
      for (int l2 = 0; l2 < 2; ++l2) {
        const float4 rv = *(const float4*)&rowf[l2][(s * 32 + e4) * 4];
        acc[l2] += wv.x * rv.x + wv.y * rv.y + wv.z * rv.z + wv.w * rv.w;
      }
    }
    const float bb = bv[f];
#pragma unroll
    for (int l2 = 0; l2 < 2; ++l2)
      vout[(size_t)(bl0 + l2) * 512 + s * 128 + f] = acc[l2] + bb;
  }
}

extern "C" void kernel_launch(void* const* d_in, const int* in_sizes, int n_in,
                              void* d_out, int out_size, void* d_ws, size_t ws_size,
                              hipStream_t stream) {
  const float* q     = (const float*)d_in[1];
  const float* key   = (const float*)d_in[2];
  const float* value = (const float*)d_in[3];
  const float* sigma = (const float*)d_in[4];
  const float* qp    = (const float*)d_in[8];
  const float* Wk    = (const float*)d_in[9];
  const float* bk    = (const float*)d_in[10];
  const float* Wv    = (const float*)d_in[11];
  const float* bv    = (const float*)d_in[12];

  float* out    = (float*)d_out;
  float* Vout   = out;
  float* sout   = out + 1048576;
  float* prior  = out + 9437184;
  float* sigout = out + 17825792;

  // ws layout (float-unit offsets), peak 10,748,160 floats = 43.0 MB. Lifetimes
  // (launch order k_prep,k1,k34,k5,k6):
  //  sbh   [0, 4,194,304)          u16[8M]    k1 w, k34 r  (bf16 unnorm P)
  //  qkb   [4,194,304, 5,242,880)  u16[2M]    prep w, k1 r
  //  vt    [5,242,880, 5,767,168)  u16[1M]    prep w, k34 r
  //  isum  [5,767,168, +8K)        f32        k1 w, k34 r
  //  wv4t  [6,291,456, 6,307,840)  f32[16K]   prep w, k6 r
  //  wkf   [6,307,840, 6,316,032)  u16[16K]   prep w, k34 r (B-frag-packed Wk)
  //  kp_bf [8,388,608, 9,568,256)  u16[2.36M] k34 w, k5 r  (18 y<=x, x>=1 slots)
  //  rt_bf [9,568,256, 10,747,904) u16[2.36M] k34 w, k5 r  (disjoint from kp_bf)
  //  colsum[10,747,904, +256)      f32        prep zero, k34 atomicAdd, k6 r
  //  vws   [0, 6,291,456)          f32        k5 w, k6 r  (48 slots of 131072;
  //                                overlays sbh/qkb/vt/isum, all dead after k34)
  float* ws     = (float*)d_ws;
  u16*   sbh    = (u16*)ws;
  u16*   qb     = (u16*)(ws + 4194304);
  u16*   kb     = qb + 1048576;
  u16*   vt     = (u16*)(ws + 5242880);
  float* isum   = ws + 5767168;
  float* wv4t   = ws + 6291456;
  u16*   wkf    = (u16*)(ws + 6307840);
  u16*   kp_bf  = (u16*)(ws + 8388608);
  u16*   rt_bf  = (u16*)(ws + 9568256);
  float* colsum = ws + 10747904;
  float* vws    = ws;

  hipLaunchKernelGGL(k_prep,      dim3(17560), dim3(256), 0, stream, q, key, value, sigma,
                     Wv, Wk, (float4*)sout, (u16*)qb, colsum, vt, (float4*)wv4t, wkf, prior, sigout);
  hipLaunchKernelGGL(k1_mfma,     dim3(512),  dim3(512), 0, stream, qb, kb, sbh, isum);
  hipLaunchKernelGGL(k34_retr_kp, dim3(640),  dim3(256), 0, stream, sbh, vt, isum, wkf, bk, kp_bf, rt_bf, colsum);
  hipLaunchKernelGGL(k5_stage2,   dim3(1536), dim3(256), 0, stream, qp, kp_bf, rt_bf, vws);
  hipLaunchKernelGGL(k6_vout,     dim3(1024), dim3(256), 0, stream, vws, (const float4*)wv4t, bv, colsum, Vout);
}